// Round 11
// baseline (588.211 us; speedup 1.0000x reference)
//
#include <hip/hip_runtime.h>
#include <cstdint>

typedef unsigned short u16;
typedef __attribute__((ext_vector_type(8))) short short8;    // 8 bf16 (MFMA A/B frag)
typedef __attribute__((ext_vector_type(4))) float floatx4;   // 16x16 C/D frag
typedef __attribute__((ext_vector_type(16))) float floatx16; // 32x32 C/D frag

__device__ __forceinline__ float b2f(u16 u) {
    union { unsigned int i; float f; } c; c.i = ((unsigned int)u) << 16; return c.f;
}
__device__ __forceinline__ u16 f2b(float f) {
    union { float f; unsigned int i; } c; c.f = f;
    unsigned int u = c.i;
    u = u + 0x7FFFu + ((u >> 16) & 1u);   // RNE
    return (u16)(u >> 16);
}
__device__ __forceinline__ float rdlane(float v, int l) {
    union { float f; int i; } c; c.f = v;
    union { int i; float f; } o; o.i = __builtin_amdgcn_readlane(c.i, l);
    return o.f;
}

// ---------------------------------------------------------------------------
// Fused Q/K/V projection GEMM. Y[m,n] = sum_k x[m,k]*W[n,k] + bias[n].
// grid (32, 24): which = blockIdx.y>>3 (0=q fp32, 1=k bf16, 2=v fp32).
// ---------------------------------------------------------------------------
__global__ __launch_bounds__(256) void gemm_qkv(
    const float* __restrict__ x,
    const float* __restrict__ Wq, const float* __restrict__ Wk, const float* __restrict__ Wv,
    const float* __restrict__ bq, const float* __restrict__ bk, const float* __restrict__ bv,
    float* __restrict__ qout, u16* __restrict__ kout, float* __restrict__ vout)
{
    __shared__ u16 xs[64 * 72];
    __shared__ u16 wsl[64 * 72];
    int tid = threadIdx.x;
    int lane = tid & 63;
    int wv = tid >> 6;
    int lo = lane & 15, hi = lane >> 4;
    int which = blockIdx.y >> 3;
    int m0 = blockIdx.x * 64, n0 = (blockIdx.y & 7) * 64;
    const float* W    = which == 0 ? Wq : (which == 1 ? Wk : Wv);
    const float* bias = which == 0 ? bq : (which == 1 ? bk : bv);

    floatx4 acc[4];
#pragma unroll
    for (int mt = 0; mt < 4; ++mt) acc[mt] = (floatx4){0.f, 0.f, 0.f, 0.f};

    for (int k0 = 0; k0 < 512; k0 += 64) {
        __syncthreads();
#pragma unroll
        for (int i = 0; i < 2; ++i) {
            int v = tid + i * 256;
            int row = v >> 3, c8 = (v & 7) * 8;
            const float* ap = x + (m0 + row) * 512 + k0 + c8;
            const float* wp = W + (n0 + row) * 512 + k0 + c8;
            float4 a0 = *(const float4*)(ap);
            float4 a1 = *(const float4*)(ap + 4);
            float4 w0 = *(const float4*)(wp);
            float4 w1v = *(const float4*)(wp + 4);
            union { u16 u[8]; uint4 q; } ca, cw;
            ca.u[0] = f2b(a0.x); ca.u[1] = f2b(a0.y); ca.u[2] = f2b(a0.z); ca.u[3] = f2b(a0.w);
            ca.u[4] = f2b(a1.x); ca.u[5] = f2b(a1.y); ca.u[6] = f2b(a1.z); ca.u[7] = f2b(a1.w);
            cw.u[0] = f2b(w0.x); cw.u[1] = f2b(w0.y); cw.u[2] = f2b(w0.z); cw.u[3] = f2b(w0.w);
            cw.u[4] = f2b(w1v.x); cw.u[5] = f2b(w1v.y); cw.u[6] = f2b(w1v.z); cw.u[7] = f2b(w1v.w);
            *(uint4*)(xs + row * 72 + c8)  = ca.q;
            *(uint4*)(wsl + row * 72 + c8) = cw.q;
        }
        __syncthreads();
#pragma unroll
        for (int ks = 0; ks < 2; ++ks) {
            short8 bfr = *(const short8*)(wsl + (wv * 16 + lo) * 72 + ks * 32 + hi * 8);
#pragma unroll
            for (int mt = 0; mt < 4; ++mt) {
                short8 afr = *(const short8*)(xs + (mt * 16 + lo) * 72 + ks * 32 + hi * 8);
                acc[mt] = __builtin_amdgcn_mfma_f32_16x16x32_bf16(afr, bfr, acc[mt], 0, 0, 0);
            }
        }
    }

    int n = n0 + wv * 16 + lo;
    float bv2 = bias[n];
    int h = n >> 6, dd = n & 63;
#pragma unroll
    for (int mt = 0; mt < 4; ++mt) {
#pragma unroll
        for (int r = 0; r < 4; ++r) {
            int m = m0 + mt * 16 + hi * 4 + r;      // C/D: row=(lane>>4)*4+reg, col=lane&15
            float y = acc[mt][r] + bv2;
            int b = m >> 10, c = m & 1023;
            int idx = (((b * 8 + h) * 1024) + c) * 64 + dd;
            if (which == 0)      qout[idx] = y;
            else if (which == 1) kout[idx] = f2b(y);
            else                 vout[idx] = y;
        }
    }
}

// ---------------------------------------------------------------------------
// Output GEMM: Y[m,n] = sum_k A[m,k]*Wo[n,k] + bo[n], fp32 out, [m*512+n].
// ---------------------------------------------------------------------------
__global__ __launch_bounds__(256) void gemm_out(
    const float* __restrict__ A, const float* __restrict__ W, const float* __restrict__ bias,
    float* __restrict__ outf)
{
    __shared__ u16 xs[64 * 72];
    __shared__ u16 wsl[64 * 72];
    int tid = threadIdx.x;
    int lane = tid & 63;
    int wv = tid >> 6;
    int lo = lane & 15, hi = lane >> 4;
    int m0 = blockIdx.x * 64, n0 = blockIdx.y * 64;

    floatx4 acc[4];
#pragma unroll
    for (int mt = 0; mt < 4; ++mt) acc[mt] = (floatx4){0.f, 0.f, 0.f, 0.f};

    for (int k0 = 0; k0 < 512; k0 += 64) {
        __syncthreads();
#pragma unroll
        for (int i = 0; i < 2; ++i) {
            int v = tid + i * 256;
            int row = v >> 3, c8 = (v & 7) * 8;
            const float* ap = A + (m0 + row) * 512 + k0 + c8;
            const float* wp = W + (n0 + row) * 512 + k0 + c8;
            float4 a0 = *(const float4*)(ap);
            float4 a1 = *(const float4*)(ap + 4);
            float4 w0 = *(const float4*)(wp);
            float4 w1v = *(const float4*)(wp + 4);
            union { u16 u[8]; uint4 q; } ca, cw;
            ca.u[0] = f2b(a0.x); ca.u[1] = f2b(a0.y); ca.u[2] = f2b(a0.z); ca.u[3] = f2b(a0.w);
            ca.u[4] = f2b(a1.x); ca.u[5] = f2b(a1.y); ca.u[6] = f2b(a1.z); ca.u[7] = f2b(a1.w);
            cw.u[0] = f2b(w0.x); cw.u[1] = f2b(w0.y); cw.u[2] = f2b(w0.z); cw.u[3] = f2b(w0.w);
            cw.u[4] = f2b(w1v.x); cw.u[5] = f2b(w1v.y); cw.u[6] = f2b(w1v.z); cw.u[7] = f2b(w1v.w);
            *(uint4*)(xs + row * 72 + c8)  = ca.q;
            *(uint4*)(wsl + row * 72 + c8) = cw.q;
        }
        __syncthreads();
#pragma unroll
        for (int ks = 0; ks < 2; ++ks) {
            short8 bfr = *(const short8*)(wsl + (wv * 16 + lo) * 72 + ks * 32 + hi * 8);
#pragma unroll
            for (int mt = 0; mt < 4; ++mt) {
                short8 afr = *(const short8*)(xs + (mt * 16 + lo) * 72 + ks * 32 + hi * 8);
                acc[mt] = __builtin_amdgcn_mfma_f32_16x16x32_bf16(afr, bfr, acc[mt], 0, 0, 0);
            }
        }
    }

    int n = n0 + wv * 16 + lo;
    float bv = bias[n];
#pragma unroll
    for (int mt = 0; mt < 4; ++mt)
#pragma unroll
        for (int r = 0; r < 4; ++r) {
            int m = m0 + mt * 16 + hi * 4 + r;
            outf[m * 512 + n] = acc[mt][r] + bv;
        }
}

// ---------------------------------------------------------------------------
// Fused second-order attention, v7: 32x32x16 MFMA orientation.
// M = e (2 tiles of 32), N = j (32 keys/iter). C/D: col=lane&31 = j,
// row = (reg&3)+8*(reg>>2)+4*(lane>>5) (+32*tile) = e.
// e-reduce: 32 in-lane fma + ONE xor-32 shuffle (was 4 shuffles).
// qp[e]+b1[e] folded as rank-1 virtual K-tile: af4=[qp_e,0..], bf4=[1,0..]
// (register constants) -> no per-iter qpb adds.
// Keeps: k prefetch dbuf, merged-rcp sigmoid-gelu, fixed-shift softmax,
// readlane PV (p sits at lane = j after the single shuffle).
// ---------------------------------------------------------------------------
__global__ __launch_bounds__(256, 3) void attn7(
    const float* __restrict__ qf, const u16* __restrict__ kb, const float* __restrict__ vf,
    const float* __restrict__ w1, const float* __restrict__ b1, const float* __restrict__ w2,
    float* __restrict__ ao)
{
    __shared__ float q_l[4 * 64];
    int tid = threadIdx.x;
    int lane = tid & 63;
    int wv = tid >> 6;
    int l31 = lane & 31, h32 = lane >> 5;
    int bh = blockIdx.x >> 8;                      // 0..15 = b*8+h
    int qi = ((blockIdx.x & 255) << 2) | wv;       // query 0..1023

    q_l[wv * 64 + lane] = qf[(bh * 1024 + qi) * 64 + lane];

    // qp[e]+b1[e] at lane=e
    float qpacc = b1[lane];
#pragma unroll
    for (int d8 = 0; d8 < 64; d8 += 8) {
        float4 wa = *(const float4*)(w1 + lane * 192 + d8);
        float4 wb = *(const float4*)(w1 + lane * 192 + d8 + 4);
        const float* q8 = q_l + wv * 64 + d8;      // wave-uniform broadcast reads
        qpacc = __builtin_fmaf(q8[0], wa.x, qpacc);
        qpacc = __builtin_fmaf(q8[1], wa.y, qpacc);
        qpacc = __builtin_fmaf(q8[2], wa.z, qpacc);
        qpacc = __builtin_fmaf(q8[3], wa.w, qpacc);
        qpacc = __builtin_fmaf(q8[4], wb.x, qpacc);
        qpacc = __builtin_fmaf(q8[5], wb.y, qpacc);
        qpacc = __builtin_fmaf(q8[6], wb.z, qpacc);
        qpacc = __builtin_fmaf(q8[7], wb.w, qpacc);
    }

    // w2c[t][r] = w2[e]*scale at e = 32t + (r&3)+8*(r>>2)+4*h32
    float w2c[2][16];
    float w2row = w2[lane] * 0.18033688f;          // w2[e] * (1/8) * log2(e)
#pragma unroll
    for (int t = 0; t < 2; ++t)
#pragma unroll
        for (int r = 0; r < 16; ++r) {
            int e = 32 * t + (r & 3) + 8 * (r >> 2) + 4 * h32;
            w2c[t][r] = __shfl(w2row, e);
        }

    // rank-1 fold frags: af4[t] = [qp[e]+b1[e], 0x7] (lower half-lanes),
    // bf4 = [1.0bf16, 0x7] (lower half-lanes)
    short8 af4[2], bf4;
    {
        union { u16 u[8]; short8 s; } cv;
#pragma unroll
        for (int i = 0; i < 8; ++i) cv.u[i] = 0;
        cv.u[0] = (h32 == 0) ? (u16)0x3F80 : (u16)0;   // bf16 1.0
        bf4 = cv.s;
#pragma unroll
        for (int t = 0; t < 2; ++t) {
            float qpv = __shfl(qpacc, l31 + 32 * t);
            union { u16 u[8]; short8 s; } ca;
#pragma unroll
            for (int i = 0; i < 8; ++i) ca.u[i] = 0;
            ca.u[0] = (h32 == 0) ? f2b(qpv) : (u16)0;
            af4[t] = ca.s;
        }
    }

    // A-frags: qw'[e = l31+32t][dd = kt*16 + h32*8 + i], bf16
    short8 af[2][4];
#pragma unroll
    for (int t = 0; t < 2; ++t) {
        const float* wr = w1 + (l31 + 32 * t) * 192;
#pragma unroll
        for (int kt = 0; kt < 4; ++kt) {
            int dd0 = kt * 16 + h32 * 8;
            float4 a0 = *(const float4*)(wr + 128 + dd0);
            float4 a1 = *(const float4*)(wr + 128 + dd0 + 4);
            float4 k0 = *(const float4*)(wr + 64 + dd0);
            float4 k1 = *(const float4*)(wr + 64 + dd0 + 4);
            const float* q8 = q_l + wv * 64 + dd0;
            union { u16 u[8]; short8 s; } cv;
            cv.u[0] = f2b(__builtin_fmaf(q8[0], a0.x, k0.x));
            cv.u[1] = f2b(__builtin_fmaf(q8[1], a0.y, k0.y));
            cv.u[2] = f2b(__builtin_fmaf(q8[2], a0.z, k0.z));
            cv.u[3] = f2b(__builtin_fmaf(q8[3], a0.w, k0.w));
            cv.u[4] = f2b(__builtin_fmaf(q8[4], a1.x, k1.x));
            cv.u[5] = f2b(__builtin_fmaf(q8[5], a1.y, k1.y));
            cv.u[6] = f2b(__builtin_fmaf(q8[6], a1.z, k1.z));
            cv.u[7] = f2b(__builtin_fmaf(q8[7], a1.w, k1.w));
            af[t][kt] = cv.s;
        }
    }

    float l_run = 0.f;
    float oa0 = 0.f, oa1 = 0.f, oa2 = 0.f, oa3 = 0.f;
    const u16*   kbase = kb + bh * 65536;
    const float* vbase = vf + bh * 65536;

    // prologue: B-frags for j0 = 0: k[j = l31][dd = kt*16 + h32*8 + i]
    short8 bf[4];
#pragma unroll
    for (int kt = 0; kt < 4; ++kt) {
        uint4 kv = *(const uint4*)(kbase + l31 * 64 + kt * 16 + h32 * 8);
        bf[kt] = *(short8*)&kv;
    }

    for (int j0 = 0; j0 < 1024; j0 += 32) {
        // prefetch next iter's B-frags
        int jn = (j0 + 32) & 1023;                 // last wraps, unused
        short8 bfn[4];
#pragma unroll
        for (int kt = 0; kt < 4; ++kt) {
            uint4 kv = *(const uint4*)(kbase + (jn + l31) * 64 + kt * 16 + h32 * 8);
            bfn[kt] = *(short8*)&kv;
        }

        // hid[e, j] = qp_e + sum_dd qw'[e,dd] k[j,dd]  (rank-1 tile is the C-init)
        floatx16 acc[2];
#pragma unroll
        for (int t = 0; t < 2; ++t) {
            acc[t] = __builtin_amdgcn_mfma_f32_32x32x16_bf16(af4[t], bf4,
                        (floatx16){0.f,0.f,0.f,0.f,0.f,0.f,0.f,0.f,0.f,0.f,0.f,0.f,0.f,0.f,0.f,0.f}, 0, 0, 0);
#pragma unroll
            for (int kt = 0; kt < 4; ++kt)
                acc[t] = __builtin_amdgcn_mfma_f32_32x32x16_bf16(af[t][kt], bf[kt], acc[t], 0, 0, 0);
        }

        // score partial: sigmoid-gelu (HW exp2) + pair-merged rcp, in-lane e-sum
        float s = 0.f;
#pragma unroll
        for (int t = 0; t < 2; ++t)
#pragma unroll
            for (int r = 0; r < 16; r += 2) {
                float x0 = acc[t][r];
                float x1 = acc[t][r + 1];
                float e0 = __builtin_amdgcn_exp2f(x0 * -2.45546696f);
                float e1 = __builtin_amdgcn_exp2f(x1 * -2.45546696f);
                float a0 = 1.0f + e0;
                float a1 = 1.0f + e1;
                float rc = __builtin_amdgcn_rcpf(a0 * a1);
                s = __builtin_fmaf(x0 * w2c[t][r], rc * a1, s);
                s = __builtin_fmaf(x1 * w2c[t][r + 1], rc * a0, s);
            }
        s += __shfl_xor(s, 32);                    // full e-sum; s[j] at lane j (&31)

        // fixed-shift softmax numerator (scores bounded |s|<~110, safe)
        float p = __builtin_amdgcn_exp2f(s - 16.0f);
        l_run += p;                                // per-lane partial (j = lane&31, 2 copies)

        // PV: p[j] at lane j -> v_readlane broadcast, SGPR fma
        const float* vrow = vbase + j0 * 64 + lane;
#pragma unroll
        for (int j = 0; j < 32; j += 4) {
            float pj0 = rdlane(p, j + 0);
            float pj1 = rdlane(p, j + 1);
            float pj2 = rdlane(p, j + 2);
            float pj3 = rdlane(p, j + 3);
            oa0 = __builtin_fmaf(pj0, vrow[(j + 0) * 64], oa0);
            oa1 = __builtin_fmaf(pj1, vrow[(j + 1) * 64], oa1);
            oa2 = __builtin_fmaf(pj2, vrow[(j + 2) * 64], oa2);
            oa3 = __builtin_fmaf(pj3, vrow[(j + 3) * 64], oa3);
        }

        // rotate pipeline
#pragma unroll
        for (int kt = 0; kt < 4; ++kt) bf[kt] = bfn[kt];
    }

    // l: each 32-lane group holds all 32 j-partials -> 5-level xor reduce
    float l = l_run;
    l += __shfl_xor(l, 1); l += __shfl_xor(l, 2);
    l += __shfl_xor(l, 4); l += __shfl_xor(l, 8);
    l += __shfl_xor(l, 16);
    float outv = (oa0 + oa1 + oa2 + oa3) * __builtin_amdgcn_rcpf(l);
    int b = bh >> 3, h = bh & 7;
    ao[(b * 1024 + qi) * 512 + h * 64 + lane] = outv;   // (B,C,D) fp32
}

// ---------------------------------------------------------------------------
extern "C" void kernel_launch(void* const* d_in, const int* in_sizes, int n_in,
                              void* d_out, int out_size, void* d_ws, size_t ws_size,
                              hipStream_t stream)
{
    (void)in_sizes; (void)n_in; (void)out_size; (void)ws_size;
    const float* x  = (const float*)d_in[0];
    const float* Wq = (const float*)d_in[1];
    const float* bq = (const float*)d_in[2];
    const float* Wk = (const float*)d_in[3];
    const float* bk = (const float*)d_in[4];
    const float* Wv = (const float*)d_in[5];
    const float* bv = (const float*)d_in[6];
    const float* w1 = (const float*)d_in[7];
    const float* b1 = (const float*)d_in[8];
    const float* w2 = (const float*)d_in[9];
    // d_in[10] = b2: scalar shift of all scores -> softmax-invariant -> unused
    const float* Wo = (const float*)d_in[11];
    const float* bo = (const float*)d_in[12];

    char* ws = (char*)d_ws;
    float* q_ws = (float*)(ws);               // 4 MB fp32 (b,h,c,d)
    u16*   k_ws = (u16*)(ws + (4u << 20));    // 2 MB bf16 (b,h,c,d)
    float* v_ws = (float*)(ws + (6u << 20));  // 4 MB fp32 (b,h,c,d)
    float* a_ws = (float*)(ws + (10u << 20)); // 4 MB fp32 (b,c,D)

    dim3 blk(256);
    hipLaunchKernelGGL(gemm_qkv, dim3(32, 24), blk, 0, stream,
                       x, Wq, Wk, Wv, bq, bk, bv, q_ws, k_ws, v_ws);
    hipLaunchKernelGGL(attn7, dim3(4096), blk, 0, stream, q_ws, k_ws, v_ws, w1, b1, w2, a_ws);
    hipLaunchKernelGGL(gemm_out, dim3(32, 8), blk, 0, stream, a_ws, Wo, bo, (float*)d_out);
}

// Round 12
// 554.761 us; speedup vs baseline: 1.0603x; 1.0603x over previous
//
#include <hip/hip_runtime.h>
#include <cstdint>

typedef unsigned short u16;
typedef __attribute__((ext_vector_type(8))) short short8;   // 8 bf16 (MFMA A/B frag)
typedef __attribute__((ext_vector_type(4))) float floatx4;  // MFMA C/D frag

__device__ __forceinline__ float b2f(u16 u) {
    union { unsigned int i; float f; } c; c.i = ((unsigned int)u) << 16; return c.f;
}
__device__ __forceinline__ u16 f2b(float f) {
    union { float f; unsigned int i; } c; c.f = f;
    unsigned int u = c.i;
    u = u + 0x7FFFu + ((u >> 16) & 1u);   // RNE
    return (u16)(u >> 16);
}
__device__ __forceinline__ float rdlane(float v, int l) {
    union { float f; int i; } c; c.f = v;
    union { int i; float f; } o; o.i = __builtin_amdgcn_readlane(c.i, l);
    return o.f;
}

// ---------------------------------------------------------------------------
// Fused Q/K/V projection GEMM. Y[m,n] = sum_k x[m,k]*W[n,k] + bias[n].
// grid (32, 24): which = blockIdx.y>>3 (0=q fp32, 1=k bf16, 2=v fp32).
// ---------------------------------------------------------------------------
__global__ __launch_bounds__(256) void gemm_qkv(
    const float* __restrict__ x,
    const float* __restrict__ Wq, const float* __restrict__ Wk, const float* __restrict__ Wv,
    const float* __restrict__ bq, const float* __restrict__ bk, const float* __restrict__ bv,
    float* __restrict__ qout, u16* __restrict__ kout, float* __restrict__ vout)
{
    __shared__ u16 xs[64 * 72];
    __shared__ u16 wsl[64 * 72];
    int tid = threadIdx.x;
    int lane = tid & 63;
    int wv = tid >> 6;
    int lo = lane & 15, hi = lane >> 4;
    int which = blockIdx.y >> 3;
    int m0 = blockIdx.x * 64, n0 = (blockIdx.y & 7) * 64;
    const float* W    = which == 0 ? Wq : (which == 1 ? Wk : Wv);
    const float* bias = which == 0 ? bq : (which == 1 ? bk : bv);

    floatx4 acc[4];
#pragma unroll
    for (int mt = 0; mt < 4; ++mt) acc[mt] = (floatx4){0.f, 0.f, 0.f, 0.f};

    for (int k0 = 0; k0 < 512; k0 += 64) {
        __syncthreads();
#pragma unroll
        for (int i = 0; i < 2; ++i) {
            int v = tid + i * 256;
            int row = v >> 3, c8 = (v & 7) * 8;
            const float* ap = x + (m0 + row) * 512 + k0 + c8;
            const float* wp = W + (n0 + row) * 512 + k0 + c8;
            float4 a0 = *(const float4*)(ap);
            float4 a1 = *(const float4*)(ap + 4);
            float4 w0 = *(const float4*)(wp);
            float4 w1v = *(const float4*)(wp + 4);
            union { u16 u[8]; uint4 q; } ca, cw;
            ca.u[0] = f2b(a0.x); ca.u[1] = f2b(a0.y); ca.u[2] = f2b(a0.z); ca.u[3] = f2b(a0.w);
            ca.u[4] = f2b(a1.x); ca.u[5] = f2b(a1.y); ca.u[6] = f2b(a1.z); ca.u[7] = f2b(a1.w);
            cw.u[0] = f2b(w0.x); cw.u[1] = f2b(w0.y); cw.u[2] = f2b(w0.z); cw.u[3] = f2b(w0.w);
            cw.u[4] = f2b(w1v.x); cw.u[5] = f2b(w1v.y); cw.u[6] = f2b(w1v.z); cw.u[7] = f2b(w1v.w);
            *(uint4*)(xs + row * 72 + c8)  = ca.q;
            *(uint4*)(wsl + row * 72 + c8) = cw.q;
        }
        __syncthreads();
#pragma unroll
        for (int ks = 0; ks < 2; ++ks) {
            short8 bfr = *(const short8*)(wsl + (wv * 16 + lo) * 72 + ks * 32 + hi * 8);
#pragma unroll
            for (int mt = 0; mt < 4; ++mt) {
                short8 afr = *(const short8*)(xs + (mt * 16 + lo) * 72 + ks * 32 + hi * 8);
                acc[mt] = __builtin_amdgcn_mfma_f32_16x16x32_bf16(afr, bfr, acc[mt], 0, 0, 0);
            }
        }
    }

    int n = n0 + wv * 16 + lo;
    float bv2 = bias[n];
    int h = n >> 6, dd = n & 63;
#pragma unroll
    for (int mt = 0; mt < 4; ++mt) {
#pragma unroll
        for (int r = 0; r < 4; ++r) {
            int m = m0 + mt * 16 + hi * 4 + r;      // C/D: row=(lane>>4)*4+reg, col=lane&15
            float y = acc[mt][r] + bv2;
            int b = m >> 10, c = m & 1023;
            int idx = (((b * 8 + h) * 1024) + c) * 64 + dd;
            if (which == 0)      qout[idx] = y;
            else if (which == 1) kout[idx] = f2b(y);
            else                 vout[idx] = y;
        }
    }
}

// ---------------------------------------------------------------------------
// Output GEMM: Y[m,n] = sum_k A[m,k]*Wo[n,k] + bo[n], fp32 out, [m*512+n].
// ---------------------------------------------------------------------------
__global__ __launch_bounds__(256) void gemm_out(
    const float* __restrict__ A, const float* __restrict__ W, const float* __restrict__ bias,
    float* __restrict__ outf)
{
    __shared__ u16 xs[64 * 72];
    __shared__ u16 wsl[64 * 72];
    int tid = threadIdx.x;
    int lane = tid & 63;
    int wv = tid >> 6;
    int lo = lane & 15, hi = lane >> 4;
    int m0 = blockIdx.x * 64, n0 = blockIdx.y * 64;

    floatx4 acc[4];
#pragma unroll
    for (int mt = 0; mt < 4; ++mt) acc[mt] = (floatx4){0.f, 0.f, 0.f, 0.f};

    for (int k0 = 0; k0 < 512; k0 += 64) {
        __syncthreads();
#pragma unroll
        for (int i = 0; i < 2; ++i) {
            int v = tid + i * 256;
            int row = v >> 3, c8 = (v & 7) * 8;
            const float* ap = A + (m0 + row) * 512 + k0 + c8;
            const float* wp = W + (n0 + row) * 512 + k0 + c8;
            float4 a0 = *(const float4*)(ap);
            float4 a1 = *(const float4*)(ap + 4);
            float4 w0 = *(const float4*)(wp);
            float4 w1v = *(const float4*)(wp + 4);
            union { u16 u[8]; uint4 q; } ca, cw;
            ca.u[0] = f2b(a0.x); ca.u[1] = f2b(a0.y); ca.u[2] = f2b(a0.z); ca.u[3] = f2b(a0.w);
            ca.u[4] = f2b(a1.x); ca.u[5] = f2b(a1.y); ca.u[6] = f2b(a1.z); ca.u[7] = f2b(a1.w);
            cw.u[0] = f2b(w0.x); cw.u[1] = f2b(w0.y); cw.u[2] = f2b(w0.z); cw.u[3] = f2b(w0.w);
            cw.u[4] = f2b(w1v.x); cw.u[5] = f2b(w1v.y); cw.u[6] = f2b(w1v.z); cw.u[7] = f2b(w1v.w);
            *(uint4*)(xs + row * 72 + c8)  = ca.q;
            *(uint4*)(wsl + row * 72 + c8) = cw.q;
        }
        __syncthreads();
#pragma unroll
        for (int ks = 0; ks < 2; ++ks) {
            short8 bfr = *(const short8*)(wsl + (wv * 16 + lo) * 72 + ks * 32 + hi * 8);
#pragma unroll
            for (int mt = 0; mt < 4; ++mt) {
                short8 afr = *(const short8*)(xs + (mt * 16 + lo) * 72 + ks * 32 + hi * 8);
                acc[mt] = __builtin_amdgcn_mfma_f32_16x16x32_bf16(afr, bfr, acc[mt], 0, 0, 0);
            }
        }
    }

    int n = n0 + wv * 16 + lo;
    float bv = bias[n];
#pragma unroll
    for (int mt = 0; mt < 4; ++mt)
#pragma unroll
        for (int r = 0; r < 4; ++r) {
            int m = m0 + mt * 16 + hi * 4 + r;
            outf[m * 512 + n] = acc[mt][r] + bv;
        }
}

// ---------------------------------------------------------------------------
// Fused second-order attention, v8 = v6 (best: 537us) + occupancy & ILP:
//  * __launch_bounds__(256,4): 128-reg budget -> 4 blocks/CU resident
//    (was 3) -> 33% more latency hiding. Total live regs ~104 < 128.
//  * split score accumulators: two 8-deep fma chains per s instead of one
//    16-deep chain.
// ---------------------------------------------------------------------------
__global__ __launch_bounds__(256, 4) void attn8(
    const float* __restrict__ qf, const u16* __restrict__ kb, const float* __restrict__ vf,
    const float* __restrict__ w1, const float* __restrict__ b1, const float* __restrict__ w2,
    float* __restrict__ ao)
{
    __shared__ float q_l[4 * 64];
    int tid = threadIdx.x;
    int lane = tid & 63;
    int wv = tid >> 6;
    int lo = lane & 15, hi = lane >> 4;
    int bh = blockIdx.x >> 8;                      // 0..15 = b*8+h
    int qi = ((blockIdx.x & 255) << 2) | wv;       // query 0..1023

    q_l[wv * 64 + lane] = qf[(bh * 1024 + qi) * 64 + lane];

    // qp[e]+b1[e] at lane=e
    float qpacc = b1[lane];
#pragma unroll
    for (int d8 = 0; d8 < 64; d8 += 8) {
        float4 wa = *(const float4*)(w1 + lane * 192 + d8);
        float4 wb = *(const float4*)(w1 + lane * 192 + d8 + 4);
        const float* q8 = q_l + wv * 64 + d8;      // wave-uniform broadcast reads
        qpacc = __builtin_fmaf(q8[0], wa.x, qpacc);
        qpacc = __builtin_fmaf(q8[1], wa.y, qpacc);
        qpacc = __builtin_fmaf(q8[2], wa.z, qpacc);
        qpacc = __builtin_fmaf(q8[3], wa.w, qpacc);
        qpacc = __builtin_fmaf(q8[4], wb.x, qpacc);
        qpacc = __builtin_fmaf(q8[5], wb.y, qpacc);
        qpacc = __builtin_fmaf(q8[6], wb.z, qpacc);
        qpacc = __builtin_fmaf(q8[7], wb.w, qpacc);
    }
    // rearrange to C/D-row indexing: e = mt*16 + hi*4 + r
    float qpb[4][4], w2c[4][4];
    float w2row = w2[lane] * 0.18033688f;          // w2[e] * (1/8) * log2(e)
#pragma unroll
    for (int mt = 0; mt < 4; ++mt)
#pragma unroll
        for (int r = 0; r < 4; ++r) {
            int e = mt * 16 + hi * 4 + r;
            qpb[mt][r] = __shfl(qpacc, e);
            w2c[mt][r] = __shfl(w2row, e);
        }

    // q pieces for frag build: qv2[ks][j] = q[ks*32 + hi*8 + j]
    float qv2[2][8];
#pragma unroll
    for (int ks = 0; ks < 2; ++ks)
#pragma unroll
        for (int j = 0; j < 8; ++j)
            qv2[ks][j] = q_l[wv * 64 + ks * 32 + hi * 8 + j];

    // A-frags: qw'[e = mt*16+lo][dd = ks*32 + hi*8 + j], bf16
    short8 af[4][2];
#pragma unroll
    for (int mt = 0; mt < 4; ++mt) {
        const float* wr = w1 + (mt * 16 + lo) * 192;
#pragma unroll
        for (int ks = 0; ks < 2; ++ks) {
            int dd0 = ks * 32 + hi * 8;
            float4 a0 = *(const float4*)(wr + 128 + dd0);
            float4 a1 = *(const float4*)(wr + 128 + dd0 + 4);
            float4 k0 = *(const float4*)(wr + 64 + dd0);
            float4 k1 = *(const float4*)(wr + 64 + dd0 + 4);
            union { u16 u[8]; short8 s; } cv;
            cv.u[0] = f2b(__builtin_fmaf(qv2[ks][0], a0.x, k0.x));
            cv.u[1] = f2b(__builtin_fmaf(qv2[ks][1], a0.y, k0.y));
            cv.u[2] = f2b(__builtin_fmaf(qv2[ks][2], a0.z, k0.z));
            cv.u[3] = f2b(__builtin_fmaf(qv2[ks][3], a0.w, k0.w));
            cv.u[4] = f2b(__builtin_fmaf(qv2[ks][4], a1.x, k1.x));
            cv.u[5] = f2b(__builtin_fmaf(qv2[ks][5], a1.y, k1.y));
            cv.u[6] = f2b(__builtin_fmaf(qv2[ks][6], a1.z, k1.z));
            cv.u[7] = f2b(__builtin_fmaf(qv2[ks][7], a1.w, k1.w));
            af[mt][ks] = cv.s;
        }
    }

    float l_run = 0.f;
    float oa0 = 0.f, oa1 = 0.f, oa2 = 0.f, oa3 = 0.f;
    const u16*   kbase = kb + bh * 65536;
    const float* vbase = vf + bh * 65536;
    const floatx4 z = (floatx4){0.f, 0.f, 0.f, 0.f};

    // prologue: load B-frags for j0 = 0
    short8 bf[2][2];
#pragma unroll
    for (int t = 0; t < 2; ++t)
#pragma unroll
        for (int ks = 0; ks < 2; ++ks) {
            uint4 kv = *(const uint4*)(kbase + (t * 16 + lo) * 64 + ks * 32 + hi * 8);
            bf[t][ks] = *(short8*)&kv;
        }

    for (int j0 = 0; j0 < 1024; j0 += 32) {
        // prefetch next iter's B-frags (latency overlapped with body below)
        int jn = (j0 + 32) & 1023;                 // last prefetch wraps, unused
        short8 bfn[2][2];
#pragma unroll
        for (int t = 0; t < 2; ++t)
#pragma unroll
            for (int ks = 0; ks < 2; ++ks) {
                uint4 kv = *(const uint4*)(kbase + (jn + t * 16 + lo) * 64 + ks * 32 + hi * 8);
                bfn[t][ks] = *(short8*)&kv;
            }

        floatx4 acc[4][2];
#pragma unroll
        for (int mt = 0; mt < 4; ++mt)
#pragma unroll
            for (int t = 0; t < 2; ++t)
                acc[mt][t] = __builtin_amdgcn_mfma_f32_16x16x32_bf16(af[mt][0], bf[t][0], z, 0, 0, 0);
#pragma unroll
        for (int mt = 0; mt < 4; ++mt)
#pragma unroll
            for (int t = 0; t < 2; ++t)
                acc[mt][t] = __builtin_amdgcn_mfma_f32_16x16x32_bf16(af[mt][1], bf[t][1], acc[mt][t], 0, 0, 0);

        // score[j]: sigmoid-gelu (HW exp2) + pair-merged rcp; split chains
        float s0a = 0.f, s0b = 0.f, s1a = 0.f, s1b = 0.f;
#pragma unroll
        for (int mt = 0; mt < 4; ++mt)
#pragma unroll
            for (int r = 0; r < 4; ++r) {
                float x0 = acc[mt][0][r] + qpb[mt][r];
                float x1 = acc[mt][1][r] + qpb[mt][r];
                float e0 = __builtin_amdgcn_exp2f(x0 * -2.45546696f);
                float e1 = __builtin_amdgcn_exp2f(x1 * -2.45546696f);
                float a0 = 1.0f + e0;
                float a1 = 1.0f + e1;
                float rc = __builtin_amdgcn_rcpf(a0 * a1);
                if (r & 1) {
                    s0a = __builtin_fmaf(x0 * w2c[mt][r], rc * a1, s0a);
                    s1a = __builtin_fmaf(x1 * w2c[mt][r], rc * a0, s1a);
                } else {
                    s0b = __builtin_fmaf(x0 * w2c[mt][r], rc * a1, s0b);
                    s1b = __builtin_fmaf(x1 * w2c[mt][r], rc * a0, s1b);
                }
            }
        float s0 = s0a + s0b, s1 = s1a + s1b;
        s0 += __shfl_xor(s0, 16); s0 += __shfl_xor(s0, 32);   // s[j=lo]
        s1 += __shfl_xor(s1, 16); s1 += __shfl_xor(s1, 32);   // s[j=16+lo]

        // fixed-shift softmax numerator (scores bounded |s|<~110, safe)
        float p0 = __builtin_amdgcn_exp2f(s0 - 16.0f);
        float p1 = __builtin_amdgcn_exp2f(s1 - 16.0f);
        l_run += p0 + p1;                          // per-lane partial (over lo)

        // PV: p[j=lane&15] lives in p0/p1 -> v_readlane broadcast, SGPR fma
        const float* vrow = vbase + j0 * 64 + lane;
#pragma unroll
        for (int j = 0; j < 16; j += 4) {
            float pa0 = rdlane(p0, j + 0), pb0 = rdlane(p1, j + 0);
            float pa1 = rdlane(p0, j + 1), pb1 = rdlane(p1, j + 1);
            float pa2 = rdlane(p0, j + 2), pb2 = rdlane(p1, j + 2);
            float pa3 = rdlane(p0, j + 3), pb3 = rdlane(p1, j + 3);
            oa0 = __builtin_fmaf(pa0, vrow[(j + 0) * 64], oa0);
            oa1 = __builtin_fmaf(pa1, vrow[(j + 1) * 64], oa1);
            oa2 = __builtin_fmaf(pa2, vrow[(j + 2) * 64], oa2);
            oa3 = __builtin_fmaf(pa3, vrow[(j + 3) * 64], oa3);
            oa0 = __builtin_fmaf(pb0, vrow[(j + 16) * 64], oa0);
            oa1 = __builtin_fmaf(pb1, vrow[(j + 17) * 64], oa1);
            oa2 = __builtin_fmaf(pb2, vrow[(j + 18) * 64], oa2);
            oa3 = __builtin_fmaf(pb3, vrow[(j + 19) * 64], oa3);
        }

        // rotate pipeline
#pragma unroll
        for (int t = 0; t < 2; ++t)
#pragma unroll
            for (int ks = 0; ks < 2; ++ks)
                bf[t][ks] = bfn[t][ks];
    }

    float l = l_run;
    l += __shfl_xor(l, 1); l += __shfl_xor(l, 2);
    l += __shfl_xor(l, 4); l += __shfl_xor(l, 8);
    float outv = (oa0 + oa1 + oa2 + oa3) * __builtin_amdgcn_rcpf(l);
    int b = bh >> 3, h = bh & 7;
    ao[(b * 1024 + qi) * 512 + h * 64 + lane] = outv;   // (B,C,D) fp32
}

// ---------------------------------------------------------------------------
extern "C" void kernel_launch(void* const* d_in, const int* in_sizes, int n_in,
                              void* d_out, int out_size, void* d_ws, size_t ws_size,
                              hipStream_t stream)
{
    (void)in_sizes; (void)n_in; (void)out_size; (void)ws_size;
    const float* x  = (const float*)d_in[0];
    const float* Wq = (const float*)d_in[1];
    const float* bq = (const float*)d_in[2];
    const float* Wk = (const float*)d_in[3];
    const float* bk = (const float*)d_in[4];
    const float* Wv = (const float*)d_in[5];
    const float* bv = (const float*)d_in[6];
    const float* w1 = (const float*)d_in[7];
    const float* b1 = (const float*)d_in[8];
    const float* w2 = (const float*)d_in[9];
    // d_in[10] = b2: scalar shift of all scores -> softmax-invariant -> unused
    const float* Wo = (const float*)d_in[11];
    const float* bo = (const float*)d_in[12];

    char* ws = (char*)d_ws;
    float* q_ws = (float*)(ws);               // 4 MB fp32 (b,h,c,d)
    u16*   k_ws = (u16*)(ws + (4u << 20));    // 2 MB bf16 (b,h,c,d)
    float* v_ws = (float*)(ws + (6u << 20));  // 4 MB fp32 (b,h,c,d)
    float* a_ws = (float*)(ws + (10u << 20)); // 4 MB fp32 (b,c,D)

    dim3 blk(256);
    hipLaunchKernelGGL(gemm_qkv, dim3(32, 24), blk, 0, stream,
                       x, Wq, Wk, Wv, bq, bk, bv, q_ws, k_ws, v_ws);
    hipLaunchKernelGGL(attn8, dim3(4096), blk, 0, stream, q_ws, k_ws, v_ws, w1, b1, w2, a_ws);
    hipLaunchKernelGGL(gemm_out, dim3(32, 8), blk, 0, stream, a_ws, Wo, bo, (float*)d_out);
}